// Round 7
// baseline (39.143 us; speedup 1.0000x reference)
//
#include <hip/hip_runtime.h>

#define NT 256

// DB4 decomposition low-pass filter (pywt convention), l0..l7
#define L0 -0.010597401784997278f
#define L1f 0.032883011666982945f
#define L2f 0.030841381835986965f
#define L3f -0.18703481171888114f
#define L4f -0.02798376941698385f
#define L5f 0.6308807679295904f
#define L6f 0.7148465705525415f
#define L7f 0.23037781330885523f

// y_lo[t] = sum_m LOR[m] * X(2t-6+m), LOR[m]=LO[7-m]
// y_hi[t] = sum_m HIR[m] * X(2t-6+m), HIR[m]=LO[m]*(m odd ? -1 : +1)

constexpr int B_ROWS = 4096;
constexpr int LVL1 = 4096, N1 = 2051, N2 = 1029, N3 = 518, N4 = 262;
constexpr size_t OFF_CA4 = 0;
constexpr size_t OFF_CD4 = (size_t)B_ROWS * N4;
constexpr size_t OFF_CD3 = OFF_CD4 + (size_t)B_ROWS * N4;
constexpr size_t OFF_CD2 = OFF_CD3 + (size_t)B_ROWS * N3;
constexpr size_t OFF_CD1 = OFF_CD2 + (size_t)B_ROWS * N2;
constexpr int WS_STRIDE = 2052;   // cA1 row stride in ws (pad 2051 -> /4 for float4)

// Clamped (symmetric-reflect) single-output pair; boundary t only. src global or LDS.
__device__ __forceinline__ void dwt_one_clamped(const float* __restrict__ src, int L, int t,
                                                float& slo, float& shi) {
    constexpr float LOR[8] = {L7f, L6f, L5f, L4f, L3f, L2f, L1f, L0};
    constexpr float HIR[8] = {L0, -L1f, L2f, -L3f, L4f, -L5f, L6f, -L7f};
    const int idx0 = 2 * t - 6;
    slo = 0.f; shi = 0.f;
#pragma unroll
    for (int m = 0; m < 8; ++m) {
        int q = idx0 + m;
        q = (q < 0) ? (-1 - q) : q;
        q = (q >= L) ? (2 * L - 1 - q) : q;
        const float v = src[q];
        slo = fmaf(LOR[m], v, slo);
        shi = fmaf(HIR[m], v, shi);
    }
}

// One DWT level, 4 outputs per thread (t0 = 4m), float4 src windows (global or LDS).
// cA -> dstA (float4 raw if !SCALE_A, else affine scalar), cD -> outD (affine folded).
template <bool SCALE_A>
__device__ __forceinline__ void dwt_level_blk(const float* __restrict__ src, int L,
                                              float* __restrict__ dstA, float wa, float ba,
                                              float* __restrict__ outD, float wd, float bd) {
    constexpr float LOR[8] = {L7f, L6f, L5f, L4f, L3f, L2f, L1f, L0};
    constexpr float HIR[8] = {L0, -L1f, L2f, -L3f, L4f, -L5f, L6f, -L7f};
    const int N = (L + 7) >> 1;
    const int Mmax = (L - 8) >> 3;     // loads [8m-8, 8m+8) stay inside [0, L)
    const int tid = threadIdx.x;

    const float h0 = wd * HIR[0], h1 = wd * HIR[1], h2 = wd * HIR[2], h3 = wd * HIR[3],
                h4 = wd * HIR[4], h5 = wd * HIR[5], h6 = wd * HIR[6], h7 = wd * HIR[7];
    const float g0 = wa * LOR[0], g1 = wa * LOR[1], g2 = wa * LOR[2], g3 = wa * LOR[3],
                g4 = wa * LOR[4], g5 = wa * LOR[5], g6 = wa * LOR[6], g7 = wa * LOR[7];

    for (int m = 1 + tid; m <= Mmax; m += NT) {
        const float4* p = reinterpret_cast<const float4*>(src) + (2 * m - 2);
        const float4 v0 = p[0], v1 = p[1], v2 = p[2], v3 = p[3];
        const float W[16] = {v0.x, v0.y, v0.z, v0.w, v1.x, v1.y, v1.z, v1.w,
                             v2.x, v2.y, v2.z, v2.w, v3.x, v3.y, v3.z, v3.w};
        float accA[4], accD[4];
#pragma unroll
        for (int o = 0; o < 4; ++o) {
            float sd = bd;
            sd = fmaf(h0, W[2 * o + 2], sd);
            sd = fmaf(h1, W[2 * o + 3], sd);
            sd = fmaf(h2, W[2 * o + 4], sd);
            sd = fmaf(h3, W[2 * o + 5], sd);
            sd = fmaf(h4, W[2 * o + 6], sd);
            sd = fmaf(h5, W[2 * o + 7], sd);
            sd = fmaf(h6, W[2 * o + 8], sd);
            sd = fmaf(h7, W[2 * o + 9], sd);
            accD[o] = sd;
            float sa;
            if (SCALE_A) {
                sa = ba;
                sa = fmaf(g0, W[2 * o + 2], sa);
                sa = fmaf(g1, W[2 * o + 3], sa);
                sa = fmaf(g2, W[2 * o + 4], sa);
                sa = fmaf(g3, W[2 * o + 5], sa);
                sa = fmaf(g4, W[2 * o + 6], sa);
                sa = fmaf(g5, W[2 * o + 7], sa);
                sa = fmaf(g6, W[2 * o + 8], sa);
                sa = fmaf(g7, W[2 * o + 9], sa);
            } else {
                sa = LOR[0] * W[2 * o + 2];
                sa = fmaf(LOR[1], W[2 * o + 3], sa);
                sa = fmaf(LOR[2], W[2 * o + 4], sa);
                sa = fmaf(LOR[3], W[2 * o + 5], sa);
                sa = fmaf(LOR[4], W[2 * o + 6], sa);
                sa = fmaf(LOR[5], W[2 * o + 7], sa);
                sa = fmaf(LOR[6], W[2 * o + 8], sa);
                sa = fmaf(LOR[7], W[2 * o + 9], sa);
            }
            accA[o] = sa;
        }
        const int t0 = 4 * m;
        if (SCALE_A) {
            dstA[t0 + 0] = accA[0]; dstA[t0 + 1] = accA[1];
            dstA[t0 + 2] = accA[2]; dstA[t0 + 3] = accA[3];
        } else {
            float4 qa; qa.x = accA[0]; qa.y = accA[1]; qa.z = accA[2]; qa.w = accA[3];
            *(reinterpret_cast<float4*>(dstA) + m) = qa;
        }
        outD[t0 + 0] = accD[0]; outD[t0 + 1] = accD[1];
        outD[t0 + 2] = accD[2]; outD[t0 + 3] = accD[3];
    }

    const int NS = N - 4 * Mmax;   // specials: t in {0..3} U {4*Mmax+4 .. N-1}
    if (tid < NS) {
        const int t = (tid < 4) ? tid : (4 * Mmax + tid);
        float slo, shi;
        dwt_one_clamped(src, L, t, slo, shi);
        dstA[t] = SCALE_A ? fmaf(wa, slo, ba) : slo;
        outD[t] = fmaf(wd, shi, bd);
    }
}

// ---------------- K1: level 1, flat streaming (no LDS, no barriers) ----------------
__global__ __launch_bounds__(NT) void lwt_l1_kernel(const float* __restrict__ x,
                                                    const float* __restrict__ w,
                                                    const float* __restrict__ bias,
                                                    float* __restrict__ out,
                                                    float* __restrict__ ws) {
    constexpr float LOR[8] = {L7f, L6f, L5f, L4f, L3f, L2f, L1f, L0};
    constexpr float HIR[8] = {L0, -L1f, L2f, -L3f, L4f, -L5f, L6f, -L7f};
    const int row = blockIdx.x;
    const int tid = threadIdx.x;
    const float* __restrict__ xr = x + (size_t)row * LVL1;
    float* __restrict__ cd1 = out + OFF_CD1 + (size_t)row * N1;
    float* __restrict__ ca1 = ws + (size_t)row * WS_STRIDE;

    const float w4 = w[4], b4 = bias[4];
    const float h0 = w4 * HIR[0], h1 = w4 * HIR[1], h2 = w4 * HIR[2], h3 = w4 * HIR[3],
                h4 = w4 * HIR[4], h5 = w4 * HIR[5], h6 = w4 * HIR[6], h7 = w4 * HIR[7];

#pragma unroll
    for (int it = 0; it < 2; ++it) {
        const int m = 1 + tid + it * NT;
        if (m <= 511) {
            const float4* p = reinterpret_cast<const float4*>(xr) + (2 * m - 2);
            const float4 v0 = p[0], v1 = p[1], v2 = p[2], v3 = p[3];
            const float W[16] = {v0.x, v0.y, v0.z, v0.w, v1.x, v1.y, v1.z, v1.w,
                                 v2.x, v2.y, v2.z, v2.w, v3.x, v3.y, v3.z, v3.w};
            float accA[4], accD[4];
#pragma unroll
            for (int o = 0; o < 4; ++o) {
                float sd = b4;
                float sa = LOR[0] * W[2 * o + 2];
                sd = fmaf(h0, W[2 * o + 2], sd);
#pragma unroll
                for (int mm = 1; mm < 8; ++mm) {
                    sd = fmaf((&h0)[0] * 0.f + // keep simple: use folded consts below
                              0.f, 0.f, sd);
                    // (loop body replaced below; see unrolled version)
                }
                // fully unrolled (compiler-friendly):
                sd = b4;
                sd = fmaf(h0, W[2 * o + 2], sd);
                sd = fmaf(h1, W[2 * o + 3], sd);
                sd = fmaf(h2, W[2 * o + 4], sd);
                sd = fmaf(h3, W[2 * o + 5], sd);
                sd = fmaf(h4, W[2 * o + 6], sd);
                sd = fmaf(h5, W[2 * o + 7], sd);
                sd = fmaf(h6, W[2 * o + 8], sd);
                sd = fmaf(h7, W[2 * o + 9], sd);
                sa = LOR[0] * W[2 * o + 2];
                sa = fmaf(LOR[1], W[2 * o + 3], sa);
                sa = fmaf(LOR[2], W[2 * o + 4], sa);
                sa = fmaf(LOR[3], W[2 * o + 5], sa);
                sa = fmaf(LOR[4], W[2 * o + 6], sa);
                sa = fmaf(LOR[5], W[2 * o + 7], sa);
                sa = fmaf(LOR[6], W[2 * o + 8], sa);
                sa = fmaf(LOR[7], W[2 * o + 9], sa);
                accD[o] = sd;
                accA[o] = sa;
            }
            const int t0 = 4 * m;
            float4 qa; qa.x = accA[0]; qa.y = accA[1]; qa.z = accA[2]; qa.w = accA[3];
            *reinterpret_cast<float4*>(ca1 + t0) = qa;
            cd1[t0 + 0] = accD[0]; cd1[t0 + 1] = accD[1];
            cd1[t0 + 2] = accD[2]; cd1[t0 + 3] = accD[3];
        }
    }
    // Specials: t in {0,1,2,3, 2048, 2049, 2050}
    if (tid < 7) {
        const int t = (tid < 4) ? tid : (2044 + tid);
        float slo, shi;
        dwt_one_clamped(xr, LVL1, t, slo, shi);
        ca1[t] = slo;
        cd1[t] = fmaf(w4, shi, b4);
    }
}

// ---------------- K234: levels 2-4 per row; L2 reads cA1 from ws (global) ----------------
__global__ __launch_bounds__(NT) void lwt_l234_kernel(const float* __restrict__ ws,
                                                      const float* __restrict__ w,
                                                      const float* __restrict__ bias,
                                                      float* __restrict__ out) {
    __shared__ __align__(16) float Q[1032];  // cA2 (1029, padded)
    __shared__ __align__(16) float R[520];   // cA3 (518, padded)
    const int row = blockIdx.x;

    const float w0 = w[0], w1 = w[1], w2 = w[2], w3 = w[3];
    const float b0 = bias[0], b1 = bias[1], b2 = bias[2], b3 = bias[3];

    const float* __restrict__ ca1 = ws + (size_t)row * WS_STRIDE;
    float* outCD2 = out + OFF_CD2 + (size_t)row * N2;
    float* outCD3 = out + OFF_CD3 + (size_t)row * N3;
    float* outCD4 = out + OFF_CD4 + (size_t)row * N4;
    float* outCA4 = out + OFF_CA4 + (size_t)row * N4;

    dwt_level_blk<false>(ca1, N1, Q, 0.f, 0.f, outCD2, w3, b3);   // 2051 -> 1029 (global src)
    __syncthreads();
    dwt_level_blk<false>(Q, N2, R, 0.f, 0.f, outCD3, w2, b2);     // 1029 -> 518
    __syncthreads();
    dwt_level_blk<true>(R, N3, outCA4, w0, b0, outCD4, w1, b1);   // 518 -> 262
}

// ---------------- Fallback: R4 monolithic kernel (used only if ws too small) ----------------
__global__ __launch_bounds__(NT) void lwt_mono_kernel(const float* __restrict__ x,
                                                      const float* __restrict__ w,
                                                      const float* __restrict__ bias,
                                                      float* __restrict__ out) {
    __shared__ __align__(16) float P[N1];
    __shared__ __align__(16) float Q[N2];
    constexpr float LOR[8] = {L7f, L6f, L5f, L4f, L3f, L2f, L1f, L0};
    constexpr float HIR[8] = {L0, -L1f, L2f, -L3f, L4f, -L5f, L6f, -L7f};
    const int row = blockIdx.x;
    const int tid = threadIdx.x;
    const float* __restrict__ xr = x + (size_t)row * LVL1;

    const float w0 = w[0], w1 = w[1], w2 = w[2], w3 = w[3], w4 = w[4];
    const float b0 = bias[0], b1 = bias[1], b2 = bias[2], b3 = bias[3], b4 = bias[4];

    float* outCD1 = out + OFF_CD1 + (size_t)row * N1;
    const float h0 = w4 * HIR[0], h1 = w4 * HIR[1], h2 = w4 * HIR[2], h3 = w4 * HIR[3],
                h4 = w4 * HIR[4], h5 = w4 * HIR[5], h6 = w4 * HIR[6], h7 = w4 * HIR[7];
    for (int m = 1 + tid; m <= 511; m += NT) {
        const float4* p = reinterpret_cast<const float4*>(xr) + (2 * m - 2);
        const float4 v0 = p[0], v1 = p[1], v2 = p[2], v3 = p[3];
        const float W[16] = {v0.x, v0.y, v0.z, v0.w, v1.x, v1.y, v1.z, v1.w,
                             v2.x, v2.y, v2.z, v2.w, v3.x, v3.y, v3.z, v3.w};
        float accA[4], accD[4];
#pragma unroll
        for (int o = 0; o < 4; ++o) {
            float sd = b4;
            sd = fmaf(h0, W[2 * o + 2], sd);
            sd = fmaf(h1, W[2 * o + 3], sd);
            sd = fmaf(h2, W[2 * o + 4], sd);
            sd = fmaf(h3, W[2 * o + 5], sd);
            sd = fmaf(h4, W[2 * o + 6], sd);
            sd = fmaf(h5, W[2 * o + 7], sd);
            sd = fmaf(h6, W[2 * o + 8], sd);
            sd = fmaf(h7, W[2 * o + 9], sd);
            accD[o] = sd;
            float sa = LOR[0] * W[2 * o + 2];
            sa = fmaf(LOR[1], W[2 * o + 3], sa);
            sa = fmaf(LOR[2], W[2 * o + 4], sa);
            sa = fmaf(LOR[3], W[2 * o + 5], sa);
            sa = fmaf(LOR[4], W[2 * o + 6], sa);
            sa = fmaf(LOR[5], W[2 * o + 7], sa);
            sa = fmaf(LOR[6], W[2 * o + 8], sa);
            sa = fmaf(LOR[7], W[2 * o + 9], sa);
            accA[o] = sa;
        }
        const int t0 = 4 * m;
        float4 qa; qa.x = accA[0]; qa.y = accA[1]; qa.z = accA[2]; qa.w = accA[3];
        *(reinterpret_cast<float4*>(P) + m) = qa;
        outCD1[t0 + 0] = accD[0]; outCD1[t0 + 1] = accD[1];
        outCD1[t0 + 2] = accD[2]; outCD1[t0 + 3] = accD[3];
    }
    if (tid < 7) {
        const int t = (tid < 4) ? tid : (2044 + tid);
        float slo, shi;
        dwt_one_clamped(xr, LVL1, t, slo, shi);
        P[t] = slo;
        outCD1[t] = fmaf(w4, shi, b4);
    }
    __syncthreads();
    dwt_level_blk<false>(P, N1, Q, 0.f, 0.f, out + OFF_CD2 + (size_t)row * N2, w3, b3);
    __syncthreads();
    dwt_level_blk<false>(Q, N2, P, 0.f, 0.f, out + OFF_CD3 + (size_t)row * N3, w2, b2);
    __syncthreads();
    dwt_level_blk<true>(P, N3, out + OFF_CA4 + (size_t)row * N4, w0, b0,
                        out + OFF_CD4 + (size_t)row * N4, w1, b1);
}

extern "C" void kernel_launch(void* const* d_in, const int* in_sizes, int n_in,
                              void* d_out, int out_size, void* d_ws, size_t ws_size,
                              hipStream_t stream) {
    const float* x = (const float*)d_in[0];
    const float* wp = (const float*)d_in[1];
    const float* bp = (const float*)d_in[2];
    float* out = (float*)d_out;
    const size_t need = (size_t)B_ROWS * WS_STRIDE * sizeof(float);
    if (ws_size >= need) {
        float* ws = (float*)d_ws;
        lwt_l1_kernel<<<dim3(B_ROWS), dim3(NT), 0, stream>>>(x, wp, bp, out, ws);
        lwt_l234_kernel<<<dim3(B_ROWS), dim3(NT), 0, stream>>>(ws, wp, bp, out);
    } else {
        lwt_mono_kernel<<<dim3(B_ROWS), dim3(NT), 0, stream>>>(x, wp, bp, out);
    }
}

// Round 8
// 27.714 us; speedup vs baseline: 1.4124x; 1.4124x over previous
//
#include <hip/hip_runtime.h>

#define NT 256

// DB4 decomposition low-pass filter (pywt convention), l0..l7
#define L0 -0.010597401784997278f
#define L1f 0.032883011666982945f
#define L2f 0.030841381835986965f
#define L3f -0.18703481171888114f
#define L4f -0.02798376941698385f
#define L5f 0.6308807679295904f
#define L6f 0.7148465705525415f
#define L7f 0.23037781330885523f

// y_lo[t] = sum_m LOR[m] * X(2t-6+m), LOR[m]=LO[7-m]
// y_hi[t] = sum_m HIR[m] * X(2t-6+m), HIR[m]=LO[m]*(m odd ? -1 : +1)

constexpr int B_ROWS = 4096;
constexpr int LVL1 = 4096, N1 = 2051, N2 = 1029, N3 = 518, N4 = 262;
constexpr size_t OFF_CA4 = 0;
constexpr size_t OFF_CD4 = (size_t)B_ROWS * N4;
constexpr size_t OFF_CD3 = OFF_CD4 + (size_t)B_ROWS * N4;
constexpr size_t OFF_CD2 = OFF_CD3 + (size_t)B_ROWS * N3;
constexpr size_t OFF_CD1 = OFF_CD2 + (size_t)B_ROWS * N2;

// LDS-only barrier: orders ds_write -> (all waves) -> ds_read WITHOUT draining
// outstanding global stores (unlike __syncthreads, which emits s_waitcnt vmcnt(0)).
// Inter-level deps are LDS-only; HBM writes keep draining under later compute.
__device__ __forceinline__ void lds_barrier() {
    asm volatile("s_waitcnt lgkmcnt(0)" ::: "memory");
    __builtin_amdgcn_s_barrier();
    asm volatile("" ::: "memory");
}

// Clamped (symmetric-reflect) single-output pair; boundary t only.
__device__ __forceinline__ void dwt_one_clamped(const float* __restrict__ src, int L, int t,
                                                float& slo, float& shi) {
    constexpr float LOR[8] = {L7f, L6f, L5f, L4f, L3f, L2f, L1f, L0};
    constexpr float HIR[8] = {L0, -L1f, L2f, -L3f, L4f, -L5f, L6f, -L7f};
    const int idx0 = 2 * t - 6;
    slo = 0.f; shi = 0.f;
#pragma unroll
    for (int m = 0; m < 8; ++m) {
        int q = idx0 + m;
        q = (q < 0) ? (-1 - q) : q;
        q = (q >= L) ? (2 * L - 1 - q) : q;
        const float v = src[q];
        slo = fmaf(LOR[m], v, slo);
        shi = fmaf(HIR[m], v, shi);
    }
}

// One DWT level from LDS, 4 outputs per thread (t0 = 4m), float4 LDS I/O.
template <bool SCALE_A>
__device__ __forceinline__ void dwt_level_blk(const float* __restrict__ src, int L,
                                              float* __restrict__ dstA, float wa, float ba,
                                              float* __restrict__ outD, float wd, float bd) {
    constexpr float LOR[8] = {L7f, L6f, L5f, L4f, L3f, L2f, L1f, L0};
    constexpr float HIR[8] = {L0, -L1f, L2f, -L3f, L4f, -L5f, L6f, -L7f};
    const int N = (L + 7) >> 1;
    const int Mmax = (L - 8) >> 3;     // loads [8m-8, 8m+8) stay inside [0, L)
    const int tid = threadIdx.x;

    const float h0 = wd * HIR[0], h1 = wd * HIR[1], h2 = wd * HIR[2], h3 = wd * HIR[3],
                h4 = wd * HIR[4], h5 = wd * HIR[5], h6 = wd * HIR[6], h7 = wd * HIR[7];
    const float g0 = wa * LOR[0], g1 = wa * LOR[1], g2 = wa * LOR[2], g3 = wa * LOR[3],
                g4 = wa * LOR[4], g5 = wa * LOR[5], g6 = wa * LOR[6], g7 = wa * LOR[7];

    for (int m = 1 + tid; m <= Mmax; m += NT) {
        const float4* p = reinterpret_cast<const float4*>(src) + (2 * m - 2);
        const float4 v0 = p[0], v1 = p[1], v2 = p[2], v3 = p[3];
        const float W[16] = {v0.x, v0.y, v0.z, v0.w, v1.x, v1.y, v1.z, v1.w,
                             v2.x, v2.y, v2.z, v2.w, v3.x, v3.y, v3.z, v3.w};
        float accA[4], accD[4];
#pragma unroll
        for (int o = 0; o < 4; ++o) {
            float sd = bd;
            sd = fmaf(h0, W[2 * o + 2], sd);
            sd = fmaf(h1, W[2 * o + 3], sd);
            sd = fmaf(h2, W[2 * o + 4], sd);
            sd = fmaf(h3, W[2 * o + 5], sd);
            sd = fmaf(h4, W[2 * o + 6], sd);
            sd = fmaf(h5, W[2 * o + 7], sd);
            sd = fmaf(h6, W[2 * o + 8], sd);
            sd = fmaf(h7, W[2 * o + 9], sd);
            accD[o] = sd;
            float sa;
            if (SCALE_A) {
                sa = ba;
                sa = fmaf(g0, W[2 * o + 2], sa);
                sa = fmaf(g1, W[2 * o + 3], sa);
                sa = fmaf(g2, W[2 * o + 4], sa);
                sa = fmaf(g3, W[2 * o + 5], sa);
                sa = fmaf(g4, W[2 * o + 6], sa);
                sa = fmaf(g5, W[2 * o + 7], sa);
                sa = fmaf(g6, W[2 * o + 8], sa);
                sa = fmaf(g7, W[2 * o + 9], sa);
            } else {
                sa = LOR[0] * W[2 * o + 2];
                sa = fmaf(LOR[1], W[2 * o + 3], sa);
                sa = fmaf(LOR[2], W[2 * o + 4], sa);
                sa = fmaf(LOR[3], W[2 * o + 5], sa);
                sa = fmaf(LOR[4], W[2 * o + 6], sa);
                sa = fmaf(LOR[5], W[2 * o + 7], sa);
                sa = fmaf(LOR[6], W[2 * o + 8], sa);
                sa = fmaf(LOR[7], W[2 * o + 9], sa);
            }
            accA[o] = sa;
        }
        const int t0 = 4 * m;
        if (SCALE_A) {
            dstA[t0 + 0] = accA[0]; dstA[t0 + 1] = accA[1];
            dstA[t0 + 2] = accA[2]; dstA[t0 + 3] = accA[3];
        } else {
            float4 qa; qa.x = accA[0]; qa.y = accA[1]; qa.z = accA[2]; qa.w = accA[3];
            *(reinterpret_cast<float4*>(dstA) + m) = qa;
        }
        outD[t0 + 0] = accD[0]; outD[t0 + 1] = accD[1];
        outD[t0 + 2] = accD[2]; outD[t0 + 3] = accD[3];
    }

    const int NS = N - 4 * Mmax;   // specials: t in {0..3} U {4*Mmax+4 .. N-1}
    if (tid < NS) {
        const int t = (tid < 4) ? tid : (4 * Mmax + tid);
        float slo, shi;
        dwt_one_clamped(src, L, t, slo, shi);
        dstA[t] = SCALE_A ? fmaf(wa, slo, ba) : slo;
        outD[t] = fmaf(wd, shi, bd);
    }
}

__global__ __launch_bounds__(NT) void lwt_kernel(const float* __restrict__ x,
                                                 const float* __restrict__ w,
                                                 const float* __restrict__ bias,
                                                 float* __restrict__ out) {
    __shared__ __align__(16) float P[N1];   // cA1, later reused for cA3
    __shared__ __align__(16) float Q[N2];   // cA2
    constexpr float LOR[8] = {L7f, L6f, L5f, L4f, L3f, L2f, L1f, L0};
    constexpr float HIR[8] = {L0, -L1f, L2f, -L3f, L4f, -L5f, L6f, -L7f};
    const int row = blockIdx.x;
    const int tid = threadIdx.x;
    const float* __restrict__ xr = x + (size_t)row * LVL1;

    const float w0 = w[0], w1 = w[1], w2 = w[2], w3 = w[3], w4 = w[4];
    const float b0 = bias[0], b1 = bias[1], b2 = bias[2], b3 = bias[3], b4 = bias[4];

    float* outCD1 = out + OFF_CD1 + (size_t)row * N1;
    const float h0 = w4 * HIR[0], h1 = w4 * HIR[1], h2 = w4 * HIR[2], h3 = w4 * HIR[3],
                h4 = w4 * HIR[4], h5 = w4 * HIR[5], h6 = w4 * HIR[6], h7 = w4 * HIR[7];

    // ---- Level 1 from GLOBAL: t0 = 4m, m = 1..511, window floats [8m-8, 8m+8). ----
    for (int m = 1 + tid; m <= 511; m += NT) {
        const float4* p = reinterpret_cast<const float4*>(xr) + (2 * m - 2);
        const float4 v0 = p[0], v1 = p[1], v2 = p[2], v3 = p[3];
        const float W[16] = {v0.x, v0.y, v0.z, v0.w, v1.x, v1.y, v1.z, v1.w,
                             v2.x, v2.y, v2.z, v2.w, v3.x, v3.y, v3.z, v3.w};
        float accA[4], accD[4];
#pragma unroll
        for (int o = 0; o < 4; ++o) {
            float sd = b4;
            sd = fmaf(h0, W[2 * o + 2], sd);
            sd = fmaf(h1, W[2 * o + 3], sd);
            sd = fmaf(h2, W[2 * o + 4], sd);
            sd = fmaf(h3, W[2 * o + 5], sd);
            sd = fmaf(h4, W[2 * o + 6], sd);
            sd = fmaf(h5, W[2 * o + 7], sd);
            sd = fmaf(h6, W[2 * o + 8], sd);
            sd = fmaf(h7, W[2 * o + 9], sd);
            accD[o] = sd;
            float sa = LOR[0] * W[2 * o + 2];
            sa = fmaf(LOR[1], W[2 * o + 3], sa);
            sa = fmaf(LOR[2], W[2 * o + 4], sa);
            sa = fmaf(LOR[3], W[2 * o + 5], sa);
            sa = fmaf(LOR[4], W[2 * o + 6], sa);
            sa = fmaf(LOR[5], W[2 * o + 7], sa);
            sa = fmaf(LOR[6], W[2 * o + 8], sa);
            sa = fmaf(LOR[7], W[2 * o + 9], sa);
            accA[o] = sa;
        }
        const int t0 = 4 * m;
        float4 qa; qa.x = accA[0]; qa.y = accA[1]; qa.z = accA[2]; qa.w = accA[3];
        *(reinterpret_cast<float4*>(P) + m) = qa;
        outCD1[t0 + 0] = accD[0]; outCD1[t0 + 1] = accD[1];
        outCD1[t0 + 2] = accD[2]; outCD1[t0 + 3] = accD[3];
    }
    if (tid < 7) {   // t in {0,1,2,3, 2048, 2049, 2050}
        const int t = (tid < 4) ? tid : (2044 + tid);
        float slo, shi;
        dwt_one_clamped(xr, LVL1, t, slo, shi);
        P[t] = slo;
        outCD1[t] = fmaf(w4, shi, b4);
    }

    lds_barrier();
    dwt_level_blk<false>(P, N1, Q, 0.f, 0.f, out + OFF_CD2 + (size_t)row * N2, w3, b3);
    lds_barrier();
    dwt_level_blk<false>(Q, N2, P, 0.f, 0.f, out + OFF_CD3 + (size_t)row * N3, w2, b2);
    lds_barrier();
    dwt_level_blk<true>(P, N3, out + OFF_CA4 + (size_t)row * N4, w0, b0,
                        out + OFF_CD4 + (size_t)row * N4, w1, b1);
}

extern "C" void kernel_launch(void* const* d_in, const int* in_sizes, int n_in,
                              void* d_out, int out_size, void* d_ws, size_t ws_size,
                              hipStream_t stream) {
    const float* x = (const float*)d_in[0];
    const float* wp = (const float*)d_in[1];
    const float* bp = (const float*)d_in[2];
    float* out = (float*)d_out;
    lwt_kernel<<<dim3(B_ROWS), dim3(NT), 0, stream>>>(x, wp, bp, out);
}